// Round 8
// baseline (98.107 us; speedup 1.0000x reference)
//
#include <hip/hip_runtime.h>
#include <cstdint>

constexpr int BB = 4, SS = 4096, EE = 512, AA = 64;
constexpr int NT = 64;     // KV tiles per batch
constexpr int NSL = 288;   // compact chunk slots per batch (CHUNK=8)

typedef __bf16 bf16x8 __attribute__((ext_vector_type(8)));
typedef float  f32x4  __attribute__((ext_vector_type(4)));
typedef float  f4     __attribute__((ext_vector_type(4)));
typedef unsigned short u16x4 __attribute__((ext_vector_type(4)));
typedef unsigned short u16x8 __attribute__((ext_vector_type(8)));

#define MFMA16(a, b, c) __builtin_amdgcn_mfma_f32_16x16x32_bf16((a), (b), (c), 0, 0, 0)

typedef const void __attribute__((address_space(1))) gvoid_t;
typedef void __attribute__((address_space(3))) lvoid_t;
__device__ __forceinline__ void gload16(const void* g, void* l) {
    __builtin_amdgcn_global_load_lds((gvoid_t*)g, (lvoid_t*)l, 16, 0, 0);
}

__device__ __forceinline__ unsigned short f2bf(float x) {
    union { float f; unsigned u; } v; v.f = x;
    unsigned r = v.u + 0x7fffu + ((v.u >> 16) & 1u);
    return (unsigned short)(r >> 16);
}
__device__ __forceinline__ float bf2f(unsigned short h) {
    union { unsigned u; float f; } v; v.u = ((unsigned)h) << 16;
    return v.f;
}
__device__ __forceinline__ bf16x8 as_bf16x8(u16x8 u) {
    union { u16x8 u; bf16x8 b; } v; v.u = u; return v.b;
}

// ---------------------------------------------------------------------------
// Kernel 0: split Wq/Wk/Wv (f32 [E,A]) into hi/lo bf16, TRANSPOSED [3][A][E]
// ---------------------------------------------------------------------------
__global__ void split_w_kernel(const float* __restrict__ Wq,
                               const float* __restrict__ Wk,
                               const float* __restrict__ Wv,
                               unsigned short* __restrict__ wt_h,
                               unsigned short* __restrict__ wt_l) {
    int idx = blockIdx.x * blockDim.x + threadIdx.x;
    if (idx >= 3 * EE * AA) return;
    int t = idx / (EE * AA);
    int rem = idx - t * (EE * AA);
    int k = rem >> 6;
    int n = rem & 63;
    const float* W = (t == 0) ? Wq : (t == 1) ? Wk : Wv;
    float x = W[k * AA + n];
    unsigned short h = f2bf(x);
    unsigned short l = f2bf(x - bf2f(h));
    int o = (t * AA + n) * EE + k;
    wt_h[o] = h;
    wt_l[o] = l;
}

// ---------------------------------------------------------------------------
// Kernel 1: projections via bf16x3-split MFMA. 64-row tiles, 768 blocks.
// X staged raw-f32 + W staged hi/lo via global_load_lds, swizzled.
// Epilogue through LDS f32 [64][65] -> coalesced u16x8 stores.
// (unchanged from R7)
// ---------------------------------------------------------------------------
__launch_bounds__(256)
__global__ void proj_kernel(const float* __restrict__ Xq,
                            const float* __restrict__ Xk,
                            const float* __restrict__ Xv,
                            const float* __restrict__ bq,
                            const float* __restrict__ bk,
                            const float* __restrict__ bv,
                            const unsigned short* __restrict__ wt_h,
                            const unsigned short* __restrict__ wt_l,
                            unsigned short* __restrict__ q_hi,
                            unsigned short* __restrict__ q_lo,
                            unsigned short* __restrict__ kv) {
    const int t = blockIdx.y;
    const float* X    = (t == 0) ? Xq : (t == 1) ? Xk : Xv;
    const float* bias = (t == 0) ? bq : (t == 1) ? bk : bv;
    const int row0 = blockIdx.x * 64;
    const int tid = threadIdx.x;
    const int lane = tid & 63, w = tid >> 6;
    const int l15 = lane & 15, l4 = lane >> 4;

    __shared__ __align__(16) char smem[32768];

    f32x4 acc[4];
#pragma unroll
    for (int j = 0; j < 4; ++j) acc[j] = (f32x4){0.f, 0.f, 0.f, 0.f};

    const unsigned short* wtH = wt_h + t * AA * EE;
    const unsigned short* wtL = wt_l + t * AA * EE;

    for (int kc0 = 0; kc0 < EE; kc0 += 64) {
#pragma unroll
        for (int s = 0; s < 4; ++s) {
            int r = w * 16 + s * 4 + (lane >> 4);
            int c4 = (lane & 15) ^ (r & 7);
            gload16(X + (size_t)(row0 + r) * EE + kc0 + c4 * 4,
                    smem + w * 4096 + s * 1024 + lane * 16);
        }
#pragma unroll
        for (int s = 0; s < 2; ++s) {
            int n = w * 16 + s * 8 + (lane >> 3);
            int cg = (lane & 7) ^ (n & 7);
            gload16(wtH + n * EE + kc0 + cg * 8,
                    smem + 16384 + w * 2048 + s * 1024 + lane * 16);
            gload16(wtL + n * EE + kc0 + cg * 8,
                    smem + 24576 + w * 2048 + s * 1024 + lane * 16);
        }
        asm volatile("s_waitcnt vmcnt(0)" ::: "memory");
        __syncthreads();

#pragma unroll
        for (int kc = 0; kc < 2; ++kc) {
            int r = w * 16 + l15;
            int c4a = (kc * 8 + l4 * 2) ^ (r & 7);
            int c4b = (kc * 8 + l4 * 2 + 1) ^ (r & 7);
            f4 va = *(const f4*)(smem + r * 256 + c4a * 16);
            f4 vb = *(const f4*)(smem + r * 256 + c4b * 16);
            u16x8 ahu, alu;
#pragma unroll
            for (int jj = 0; jj < 4; ++jj) {
                unsigned short h0 = f2bf(va[jj]);
                ahu[jj] = h0;
                alu[jj] = f2bf(va[jj] - bf2f(h0));
                unsigned short h1 = f2bf(vb[jj]);
                ahu[jj + 4] = h1;
                alu[jj + 4] = f2bf(vb[jj] - bf2f(h1));
            }
            bf16x8 a_h = as_bf16x8(ahu), a_l = as_bf16x8(alu);
#pragma unroll
            for (int j = 0; j < 4; ++j) {
                int n = j * 16 + l15;
                int byteB = n * 128 + (((kc * 4 + l4) ^ (n & 7)) << 4);
                bf16x8 b_h = as_bf16x8(*(const u16x8*)(smem + 16384 + byteB));
                bf16x8 b_l = as_bf16x8(*(const u16x8*)(smem + 24576 + byteB));
                acc[j] = MFMA16(a_h, b_h, acc[j]);
                acc[j] = MFMA16(a_h, b_l, acc[j]);
                acc[j] = MFMA16(a_l, b_h, acc[j]);
            }
        }
        __syncthreads();
    }

    float* stage = (float*)smem;
#pragma unroll
    for (int j = 0; j < 4; ++j) {
        int n = j * 16 + l15;
        float bv_ = bias[n];
#pragma unroll
        for (int reg = 0; reg < 4; ++reg) {
            int r = w * 16 + l4 * 4 + reg;
            stage[r * 65 + n] = acc[j][reg] + bv_;
        }
    }
    __syncthreads();

    if (t == 0) {
        int row = tid >> 2, n0 = (tid & 3) * 16;
        u16x8 h0, l0, h1, l1;
#pragma unroll
        for (int k = 0; k < 8; ++k) {
            float v = stage[row * 65 + n0 + k];
            unsigned short hh = f2bf(v);
            h0[k] = hh; l0[k] = f2bf(v - bf2f(hh));
        }
#pragma unroll
        for (int k = 0; k < 8; ++k) {
            float v = stage[row * 65 + n0 + 8 + k];
            unsigned short hh = f2bf(v);
            h1[k] = hh; l1[k] = f2bf(v - bf2f(hh));
        }
        size_t o = (size_t)(row0 + row) * AA + n0;
        *(u16x8*)(q_hi + o) = h0; *(u16x8*)(q_hi + o + 8) = h1;
        *(u16x8*)(q_lo + o) = l0; *(u16x8*)(q_lo + o + 8) = l1;
    } else {
        const int bb = row0 >> 12, kt = (row0 & 4095) >> 6;
        const size_t base = ((size_t)(bb * NT + kt) << 14) + (t == 2 ? 8192 : 0);
        const int f = tid >> 5;
#pragma unroll
        for (int p = 0; p < 2; ++p) {
            int lane2 = (tid & 31) * 2 + p;
            u16x8 h, l;
            if (t == 1) {
                int n0 = (f >> 2) * 32 + (lane2 >> 4) * 8;
                int tt = (f & 3) * 16 + (lane2 & 15);
#pragma unroll
                for (int jj = 0; jj < 8; ++jj) {
                    float v = stage[tt * 65 + n0 + jj];
                    unsigned short hh = f2bf(v);
                    h[jj] = hh; l[jj] = f2bf(v - bf2f(hh));
                }
            } else {
                int tt0 = (f >> 2) * 32 + (lane2 >> 4) * 8;
                int n = (f & 3) * 16 + (lane2 & 15);
#pragma unroll
                for (int jj = 0; jj < 8; ++jj) {
                    float v = stage[(tt0 + jj) * 65 + n];
                    unsigned short hh = f2bf(v);
                    h[jj] = hh; l[jj] = f2bf(v - bf2f(hh));
                }
            }
            size_t o = base + f * 512 + lane2 * 8;
            *(u16x8*)(kv + o) = h;
            *(u16x8*)(kv + o + 4096) = l;
        }
    }
}

// ---------------------------------------------------------------------------
// Kernel 2: per-tile V column sums -> exclusive suffix over tiles.
// ---------------------------------------------------------------------------
__launch_bounds__(64)
__global__ void sufv_kernel(const unsigned short* __restrict__ kv,
                            float* __restrict__ sufv) {
    const int b = blockIdx.x >> 6;
    const int a = blockIdx.x & 63;
    const int t = threadIdx.x;
    __shared__ float sums[64];
    const size_t tb = ((size_t)(b * NT + t) << 14) + 8192;
    const int j = a >> 4, l15i = a & 15;
    float s = 0.f;
#pragma unroll
    for (int c2 = 0; c2 < 2; ++c2) {
#pragma unroll
        for (int l4i = 0; l4i < 4; ++l4i) {
            size_t off = tb + (((c2 * 4 + j) * 64 + l4i * 16 + l15i) << 3);
            u16x8 h = *(const u16x8*)(kv + off);
            u16x8 l = *(const u16x8*)(kv + off + 4096);
#pragma unroll
            for (int q = 0; q < 8; ++q) s += bf2f(h[q]) + bf2f(l[q]);
        }
    }
    sums[t] = s;
    __syncthreads();
    float suf = 0.f;
    for (int jj = t + 1; jj < 64; ++jj) suf += sums[jj];
    sufv[((size_t)(b * 64 + a)) * 64 + t] = suf;
}

// ---------------------------------------------------------------------------
// Kernel 3: split-KV attention chunk. DOUBLE-BUFFERED LDS staging (T3 2-phase
// recipe): issue stage(t+1) before compute(t); ONE vmcnt(0)+barrier per tile.
// s_setprio(1) around MFMA clusters (T5; independent blocks -> applies).
// ---------------------------------------------------------------------------
__launch_bounds__(256)
__global__ void attn_chunk_kernel(const unsigned short* __restrict__ q_hi,
                                  const unsigned short* __restrict__ q_lo,
                                  const unsigned short* __restrict__ kv,
                                  float* __restrict__ facc_part,
                                  float* __restrict__ l_part) {
    const int bxr = (NSL - 1) - blockIdx.x;  // heavy-first
    const int b = blockIdx.y;
    int g = 7;
    while (4 * g * (g + 1) > bxr) --g;
    const int r_ = bxr - 4 * g * (g + 1);
    const int q_ = (int)((float)r_ * (1.0f / (float)(g + 1)) + 1e-4f);
    const int i  = g * 8 + q_;
    const int c  = r_ - q_ * (g + 1);
    const int t_begin = c * 8;
    const int t_end   = (t_begin + 8 < i + 1) ? t_begin + 8 : i + 1;

    const int tid = threadIdx.x;
    const int lane = tid & 63, w = tid >> 6;
    const int l15 = lane & 15, l4 = lane >> 4;

    __shared__ __align__(16) unsigned short kvbuf[2][16384];  // 2 x 32 KB
    __shared__ __align__(16) unsigned short plds[4][1024];    // per-wave P

    // Q fragments (precomputed bf16 hi/lo)
    bf16x8 qh[2], ql[2];
    {
        size_t qrow = (size_t)(b * SS + i * 64 + w * 16 + l15) * AA;
#pragma unroll
        for (int kc = 0; kc < 2; ++kc) {
            qh[kc] = as_bf16x8(*(const u16x8*)(q_hi + qrow + kc * 32 + l4 * 8));
            ql[kc] = as_bf16x8(*(const u16x8*)(q_lo + qrow + kc * 32 + l4 * 8));
        }
    }

    f32x4 facc[4];
#pragma unroll
    for (int j = 0; j < 4; ++j) facc[j] = (f32x4){0.f, 0.f, 0.f, 0.f};
    float lsum[4] = {0.f, 0.f, 0.f, 0.f};

    const size_t gbase = ((size_t)(b * NT)) << 15;
    const int goff = w * 8192 + lane * 16;
    const int loff = w * 8192;

    // ---- prologue: stage first tile into buf 0 ----
    {
        const char* gt = (const char*)kv + gbase + (((size_t)t_begin) << 15) + goff;
        char* lw = (char*)kvbuf[0] + loff;
#pragma unroll
        for (int s = 0; s < 8; ++s) gload16(gt + s * 1024, lw + s * 1024);
    }
    asm volatile("s_waitcnt vmcnt(0)" ::: "memory");
    __syncthreads();

    int cur = 0;
    for (int kt = t_begin; kt < t_end; ++kt) {
        const bool more = (kt + 1 < t_end);
        // ---- issue next tile's stage into the other buffer ----
        if (more) {
            const char* gt = (const char*)kv + gbase + (((size_t)(kt + 1)) << 15) + goff;
            char* lw = (char*)kvbuf[cur ^ 1] + loff;
#pragma unroll
            for (int s = 0; s < 8; ++s) gload16(gt + s * 1024, lw + s * 1024);
        }

        const char* lb = (const char*)kvbuf[cur];

        // ---- QK^T (bf16x3 split) from LDS ----
        f32x4 sc[4];
#pragma unroll
        for (int j = 0; j < 4; ++j) sc[j] = (f32x4){0.f, 0.f, 0.f, 0.f};
        __builtin_amdgcn_s_setprio(1);
#pragma unroll
        for (int kc = 0; kc < 2; ++kc) {
#pragma unroll
            for (int j2 = 0; j2 < 4; ++j2) {
                int f = kc * 4 + j2;
                bf16x8 h = as_bf16x8(*(const u16x8*)(lb + f * 1024 + lane * 16));
                bf16x8 l = as_bf16x8(*(const u16x8*)(lb + 8192 + f * 1024 + lane * 16));
                sc[j2] = MFMA16(qh[kc], h, sc[j2]);
                sc[j2] = MFMA16(qh[kc], l, sc[j2]);
                sc[j2] = MFMA16(ql[kc], h, sc[j2]);
            }
        }
        __builtin_amdgcn_s_setprio(0);

        // ---- scale, multiplicative mask (diag tile only), exp ----
        const bool diag = (kt == i);
        float pv[4][4];
#pragma unroll
        for (int j2 = 0; j2 < 4; ++j2) {
#pragma unroll
            for (int reg = 0; reg < 4; ++reg) {
                float s = sc[j2][reg] * 0.125f;
                if (diag) {
                    int qr = w * 16 + l4 * 4 + reg;
                    int tg = j2 * 16 + l15;
                    if (tg > qr) s = 0.f;
                }
                float p = __expf(s);
                pv[j2][reg] = p;
                lsum[reg] += p;
            }
        }
        // ---- P -> per-wave LDS (bf16, swizzled; no barrier needed) ----
#pragma unroll
        for (int j2 = 0; j2 < 4; ++j2) {
#pragma unroll
            for (int reg = 0; reg < 4; ++reg) {
                int row = l4 * 4 + reg, col = j2 * 16 + l15;
                int byte = (row * 128 + col * 2) ^ ((row & 7) << 4);
                *(unsigned short*)((char*)plds[w] + byte) = f2bf(pv[j2][reg]);
            }
        }
        // ---- PV: facc += P @ (Vhi + Vlo), V from LDS ----
        __builtin_amdgcn_s_setprio(1);
#pragma unroll
        for (int c2 = 0; c2 < 2; ++c2) {
            int byteA = (l15 * 128 + c2 * 64 + l4 * 16) ^ ((l15 & 7) << 4);
            bf16x8 pf = as_bf16x8(*(const u16x8*)((const char*)plds[w] + byteA));
#pragma unroll
            for (int j = 0; j < 4; ++j) {
                int f = c2 * 4 + j;
                bf16x8 vh = as_bf16x8(*(const u16x8*)(lb + 16384 + f * 1024 + lane * 16));
                bf16x8 vl = as_bf16x8(*(const u16x8*)(lb + 24576 + f * 1024 + lane * 16));
                facc[j] = MFMA16(pf, vh, facc[j]);
                facc[j] = MFMA16(pf, vl, facc[j]);
            }
        }
        __builtin_amdgcn_s_setprio(0);

        // ---- tile boundary: wait for next stage + protect buf reuse ----
        if (more) {
            asm volatile("s_waitcnt vmcnt(0)" ::: "memory");
            __syncthreads();
            cur ^= 1;
        }
    }

    // ---- deferred l-reduce (within 16-lane groups) ----
#pragma unroll
    for (int reg = 0; reg < 4; ++reg) {
        float rs = lsum[reg];
#pragma unroll
        for (int off = 1; off < 16; off <<= 1) rs += __shfl_xor(rs, off);
        lsum[reg] = rs;
    }

    // ---- write partials (slot = b*NSL + bxr) ----
    const size_t slot = (size_t)b * NSL + bxr;
    float* fp = facc_part + slot * 4096;
#pragma unroll
    for (int j = 0; j < 4; ++j) {
#pragma unroll
        for (int reg = 0; reg < 4; ++reg) {
            int row = w * 16 + l4 * 4 + reg, a = j * 16 + l15;
            fp[row * 64 + a] = facc[j][reg];
        }
    }
    if (l15 == 0) {
#pragma unroll
        for (int reg = 0; reg < 4; ++reg)
            l_part[slot * 64 + w * 16 + l4 * 4 + reg] = lsum[reg];
    }
}

// ---------------------------------------------------------------------------
// Kernel 4: combine partials + closed-form masked region, write output (f4).
// ---------------------------------------------------------------------------
__launch_bounds__(256)
__global__ void combine_kernel(const float* __restrict__ facc_part,
                               const float* __restrict__ l_part,
                               const float* __restrict__ sufv,
                               float* __restrict__ out) {
    const int i = blockIdx.x;
    const int b = blockIdx.y;
    const int tid = threadIdx.x;
    const int g = i >> 3;
    const int nch = g + 1;
    const size_t slot0 = (size_t)b * NSL + 4 * g * (g + 1) + (i & 7) * nch;
    __shared__ float linv[64];
    __shared__ float sv[64];
    if (tid < 64) {
        float l = (float)(64 * (NT - 1 - i));
        for (int cc = 0; cc < nch; ++cc) l += l_part[(slot0 + cc) * 64 + tid];
        linv[tid] = 1.f / l;
        sv[tid] = sufv[((size_t)(b * 64 + tid)) * 64 + i];
    }
    __syncthreads();
    float* ob = out + ((size_t)(b * SS + i * 64)) * AA;
#pragma unroll
    for (int k = 0; k < 4; ++k) {
        int e = (tid + k * 256) * 4;
        int row = e >> 6, a = e & 63;
        f4 acc = {sv[a], sv[a + 1], sv[a + 2], sv[a + 3]};
        for (int cc = 0; cc < nch; ++cc) {
            f4 v = *(const f4*)(facc_part + (slot0 + cc) * 4096 + e);
            acc += v;
        }
        acc *= linv[row];
        *(f4*)(ob + e) = acc;
    }
}

// ---------------------------------------------------------------------------
extern "C" void kernel_launch(void* const* d_in, const int* in_sizes, int n_in,
                              void* d_out, int out_size, void* d_ws, size_t ws_size,
                              hipStream_t stream) {
    const float* query = (const float*)d_in[0];
    const float* key   = (const float*)d_in[1];
    const float* value = (const float*)d_in[2];
    const float* Wq    = (const float*)d_in[3];
    const float* bq    = (const float*)d_in[4];
    const float* Wk    = (const float*)d_in[5];
    const float* bk    = (const float*)d_in[6];
    const float* Wv    = (const float*)d_in[7];
    const float* bv    = (const float*)d_in[8];

    char* ws = (char*)d_ws;
    const size_t MB = 1u << 20;
    unsigned short* q_hi = (unsigned short*)(ws + 0 * MB);    // 2 MB
    unsigned short* q_lo = (unsigned short*)(ws + 2 * MB);    // 2 MB
    unsigned short* kv   = (unsigned short*)(ws + 4 * MB);    // 8 MB
    float* sufv      = (float*)(ws + 12 * MB);                // 64 KB
    float* l_part    = (float*)(ws + 13 * MB);                // 295 KB
    float* facc_part = (float*)(ws + 14 * MB);                // 18.9 MB
    unsigned short* wt_h = (unsigned short*)(ws + 34 * MB);   // 192 KB
    unsigned short* wt_l = wt_h + 3 * AA * EE;                // 192 KB

    split_w_kernel<<<(3 * EE * AA + 255) / 256, 256, 0, stream>>>(Wq, Wk, Wv, wt_h, wt_l);
    proj_kernel<<<dim3(BB * SS / 64, 3), 256, 0, stream>>>(
        query, key, value, bq, bk, bv, wt_h, wt_l, q_hi, q_lo, kv);
    sufv_kernel<<<BB * AA, 64, 0, stream>>>(kv, sufv);
    attn_chunk_kernel<<<dim3(NSL, BB), 256, 0, stream>>>(
        q_hi, q_lo, kv, facc_part, l_part);
    combine_kernel<<<dim3(NT, BB), 256, 0, stream>>>(facc_part, l_part, sufv, (float*)d_out);
}

// Round 9
// 90.324 us; speedup vs baseline: 1.0862x; 1.0862x over previous
//
#include <hip/hip_runtime.h>
#include <cstdint>

constexpr int BB = 4, SS = 4096, EE = 512, AA = 64;
constexpr int NT = 64;     // KV tiles per batch
constexpr int NSL = 288;   // compact chunk slots per batch (CHUNK=8)

typedef __bf16 bf16x8 __attribute__((ext_vector_type(8)));
typedef float  f32x4  __attribute__((ext_vector_type(4)));
typedef float  f4     __attribute__((ext_vector_type(4)));
typedef unsigned short u16x4 __attribute__((ext_vector_type(4)));
typedef unsigned short u16x8 __attribute__((ext_vector_type(8)));

#define MFMA16(a, b, c) __builtin_amdgcn_mfma_f32_16x16x32_bf16((a), (b), (c), 0, 0, 0)

typedef const void __attribute__((address_space(1))) gvoid_t;
typedef void __attribute__((address_space(3))) lvoid_t;
__device__ __forceinline__ void gload16(const void* g, void* l) {
    __builtin_amdgcn_global_load_lds((gvoid_t*)g, (lvoid_t*)l, 16, 0, 0);
}

__device__ __forceinline__ unsigned short f2bf(float x) {
    union { float f; unsigned u; } v; v.f = x;
    unsigned r = v.u + 0x7fffu + ((v.u >> 16) & 1u);
    return (unsigned short)(r >> 16);
}
__device__ __forceinline__ float bf2f(unsigned short h) {
    union { unsigned u; float f; } v; v.u = ((unsigned)h) << 16;
    return v.f;
}
__device__ __forceinline__ bf16x8 as_bf16x8(u16x8 u) {
    union { u16x8 u; bf16x8 b; } v; v.u = u; return v.b;
}

// ---------------------------------------------------------------------------
// Kernel 0: split Wq/Wk/Wv (f32 [E,A]) into hi/lo bf16, TRANSPOSED [3][A][E]
// ---------------------------------------------------------------------------
__global__ void split_w_kernel(const float* __restrict__ Wq,
                               const float* __restrict__ Wk,
                               const float* __restrict__ Wv,
                               unsigned short* __restrict__ wt_h,
                               unsigned short* __restrict__ wt_l) {
    int idx = blockIdx.x * blockDim.x + threadIdx.x;
    if (idx >= 3 * EE * AA) return;
    int t = idx / (EE * AA);
    int rem = idx - t * (EE * AA);
    int k = rem >> 6;
    int n = rem & 63;
    const float* W = (t == 0) ? Wq : (t == 1) ? Wk : Wv;
    float x = W[k * AA + n];
    unsigned short h = f2bf(x);
    unsigned short l = f2bf(x - bf2f(h));
    int o = (t * AA + n) * EE + k;
    wt_h[o] = h;
    wt_l[o] = l;
}

// ---------------------------------------------------------------------------
// Kernel 1: projections via bf16x3-split MFMA (unchanged from R7).
// ---------------------------------------------------------------------------
__launch_bounds__(256)
__global__ void proj_kernel(const float* __restrict__ Xq,
                            const float* __restrict__ Xk,
                            const float* __restrict__ Xv,
                            const float* __restrict__ bq,
                            const float* __restrict__ bk,
                            const float* __restrict__ bv,
                            const unsigned short* __restrict__ wt_h,
                            const unsigned short* __restrict__ wt_l,
                            unsigned short* __restrict__ q_hi,
                            unsigned short* __restrict__ q_lo,
                            unsigned short* __restrict__ kv) {
    const int t = blockIdx.y;
    const float* X    = (t == 0) ? Xq : (t == 1) ? Xk : Xv;
    const float* bias = (t == 0) ? bq : (t == 1) ? bk : bv;
    const int row0 = blockIdx.x * 64;
    const int tid = threadIdx.x;
    const int lane = tid & 63, w = tid >> 6;
    const int l15 = lane & 15, l4 = lane >> 4;

    __shared__ __align__(16) char smem[32768];

    f32x4 acc[4];
#pragma unroll
    for (int j = 0; j < 4; ++j) acc[j] = (f32x4){0.f, 0.f, 0.f, 0.f};

    const unsigned short* wtH = wt_h + t * AA * EE;
    const unsigned short* wtL = wt_l + t * AA * EE;

    for (int kc0 = 0; kc0 < EE; kc0 += 64) {
#pragma unroll
        for (int s = 0; s < 4; ++s) {
            int r = w * 16 + s * 4 + (lane >> 4);
            int c4 = (lane & 15) ^ (r & 7);
            gload16(X + (size_t)(row0 + r) * EE + kc0 + c4 * 4,
                    smem + w * 4096 + s * 1024 + lane * 16);
        }
#pragma unroll
        for (int s = 0; s < 2; ++s) {
            int n = w * 16 + s * 8 + (lane >> 3);
            int cg = (lane & 7) ^ (n & 7);
            gload16(wtH + n * EE + kc0 + cg * 8,
                    smem + 16384 + w * 2048 + s * 1024 + lane * 16);
            gload16(wtL + n * EE + kc0 + cg * 8,
                    smem + 24576 + w * 2048 + s * 1024 + lane * 16);
        }
        asm volatile("s_waitcnt vmcnt(0)" ::: "memory");
        __syncthreads();

#pragma unroll
        for (int kc = 0; kc < 2; ++kc) {
            int r = w * 16 + l15;
            int c4a = (kc * 8 + l4 * 2) ^ (r & 7);
            int c4b = (kc * 8 + l4 * 2 + 1) ^ (r & 7);
            f4 va = *(const f4*)(smem + r * 256 + c4a * 16);
            f4 vb = *(const f4*)(smem + r * 256 + c4b * 16);
            u16x8 ahu, alu;
#pragma unroll
            for (int jj = 0; jj < 4; ++jj) {
                unsigned short h0 = f2bf(va[jj]);
                ahu[jj] = h0;
                alu[jj] = f2bf(va[jj] - bf2f(h0));
                unsigned short h1 = f2bf(vb[jj]);
                ahu[jj + 4] = h1;
                alu[jj + 4] = f2bf(vb[jj] - bf2f(h1));
            }
            bf16x8 a_h = as_bf16x8(ahu), a_l = as_bf16x8(alu);
#pragma unroll
            for (int j = 0; j < 4; ++j) {
                int n = j * 16 + l15;
                int byteB = n * 128 + (((kc * 4 + l4) ^ (n & 7)) << 4);
                bf16x8 b_h = as_bf16x8(*(const u16x8*)(smem + 16384 + byteB));
                bf16x8 b_l = as_bf16x8(*(const u16x8*)(smem + 24576 + byteB));
                acc[j] = MFMA16(a_h, b_h, acc[j]);
                acc[j] = MFMA16(a_h, b_l, acc[j]);
                acc[j] = MFMA16(a_l, b_h, acc[j]);
            }
        }
        __syncthreads();
    }

    float* stage = (float*)smem;
#pragma unroll
    for (int j = 0; j < 4; ++j) {
        int n = j * 16 + l15;
        float bv_ = bias[n];
#pragma unroll
        for (int reg = 0; reg < 4; ++reg) {
            int r = w * 16 + l4 * 4 + reg;
            stage[r * 65 + n] = acc[j][reg] + bv_;
        }
    }
    __syncthreads();

    if (t == 0) {
        int row = tid >> 2, n0 = (tid & 3) * 16;
        u16x8 h0, l0, h1, l1;
#pragma unroll
        for (int k = 0; k < 8; ++k) {
            float v = stage[row * 65 + n0 + k];
            unsigned short hh = f2bf(v);
            h0[k] = hh; l0[k] = f2bf(v - bf2f(hh));
        }
#pragma unroll
        for (int k = 0; k < 8; ++k) {
            float v = stage[row * 65 + n0 + 8 + k];
            unsigned short hh = f2bf(v);
            h1[k] = hh; l1[k] = f2bf(v - bf2f(hh));
        }
        size_t o = (size_t)(row0 + row) * AA + n0;
        *(u16x8*)(q_hi + o) = h0; *(u16x8*)(q_hi + o + 8) = h1;
        *(u16x8*)(q_lo + o) = l0; *(u16x8*)(q_lo + o + 8) = l1;
    } else {
        const int bb = row0 >> 12, kt = (row0 & 4095) >> 6;
        const size_t base = ((size_t)(bb * NT + kt) << 14) + (t == 2 ? 8192 : 0);
        const int f = tid >> 5;
#pragma unroll
        for (int p = 0; p < 2; ++p) {
            int lane2 = (tid & 31) * 2 + p;
            u16x8 h, l;
            if (t == 1) {
                int n0 = (f >> 2) * 32 + (lane2 >> 4) * 8;
                int tt = (f & 3) * 16 + (lane2 & 15);
#pragma unroll
                for (int jj = 0; jj < 8; ++jj) {
                    float v = stage[tt * 65 + n0 + jj];
                    unsigned short hh = f2bf(v);
                    h[jj] = hh; l[jj] = f2bf(v - bf2f(hh));
                }
            } else {
                int tt0 = (f >> 2) * 32 + (lane2 >> 4) * 8;
                int n = (f & 3) * 16 + (lane2 & 15);
#pragma unroll
                for (int jj = 0; jj < 8; ++jj) {
                    float v = stage[(tt0 + jj) * 65 + n];
                    unsigned short hh = f2bf(v);
                    h[jj] = hh; l[jj] = f2bf(v - bf2f(hh));
                }
            }
            size_t o = base + f * 512 + lane2 * 8;
            *(u16x8*)(kv + o) = h;
            *(u16x8*)(kv + o + 4096) = l;
        }
    }
}

// ---------------------------------------------------------------------------
// Kernel 2: per-tile V column sums -> exclusive suffix over tiles.
// ---------------------------------------------------------------------------
__launch_bounds__(64)
__global__ void sufv_kernel(const unsigned short* __restrict__ kv,
                            float* __restrict__ sufv) {
    const int b = blockIdx.x >> 6;
    const int a = blockIdx.x & 63;
    const int t = threadIdx.x;
    __shared__ float sums[64];
    const size_t tb = ((size_t)(b * NT + t) << 14) + 8192;
    const int j = a >> 4, l15i = a & 15;
    float s = 0.f;
#pragma unroll
    for (int c2 = 0; c2 < 2; ++c2) {
#pragma unroll
        for (int l4i = 0; l4i < 4; ++l4i) {
            size_t off = tb + (((c2 * 4 + j) * 64 + l4i * 16 + l15i) << 3);
            u16x8 h = *(const u16x8*)(kv + off);
            u16x8 l = *(const u16x8*)(kv + off + 4096);
#pragma unroll
            for (int q = 0; q < 8; ++q) s += bf2f(h[q]) + bf2f(l[q]);
        }
    }
    sums[t] = s;
    __syncthreads();
    float suf = 0.f;
    for (int jj = t + 1; jj < 64; ++jj) suf += sums[jj];
    sufv[((size_t)(b * 64 + a)) * 64 + t] = suf;
}

// ---------------------------------------------------------------------------
// Kernel 3: split-KV attention chunk. Single 32KB kvbuf (4 blocks/CU cap) +
// T14 async-STAGE split: tile t+1 global->reg loads issued BEFORE tile t's
// compute, ds_write after end-of-compute barrier. Swapped-QK (mfma(K,Q)) so
// each lane holds 4 consecutive t per j2 -> packed 8B P-writes + 2-shfl
// l-reduce. setprio(1) on MFMA clusters.
// ---------------------------------------------------------------------------
__launch_bounds__(256)
__global__ void attn_chunk_kernel(const unsigned short* __restrict__ q_hi,
                                  const unsigned short* __restrict__ q_lo,
                                  const unsigned short* __restrict__ kv,
                                  float* __restrict__ facc_part,
                                  float* __restrict__ l_part) {
    const int bxr = (NSL - 1) - blockIdx.x;  // heavy-first
    const int b = blockIdx.y;
    int g = 7;
    while (4 * g * (g + 1) > bxr) --g;
    const int r_ = bxr - 4 * g * (g + 1);
    const int q_ = (int)((float)r_ * (1.0f / (float)(g + 1)) + 1e-4f);
    const int i  = g * 8 + q_;
    const int c  = r_ - q_ * (g + 1);
    const int t_begin = c * 8;
    const int t_end   = (t_begin + 8 < i + 1) ? t_begin + 8 : i + 1;

    const int tid = threadIdx.x;
    const int lane = tid & 63, w = tid >> 6;
    const int l15 = lane & 15, l4 = lane >> 4;

    __shared__ __align__(16) unsigned short kvbuf[16384];   // 32 KB: kh|kl|vh|vl
    __shared__ __align__(16) unsigned short plds[4][1024];  // per-wave P [16][64]

    // Q fragments (precomputed bf16 hi/lo)
    bf16x8 qh[2], ql[2];
    {
        size_t qrow = (size_t)(b * SS + i * 64 + w * 16 + l15) * AA;
#pragma unroll
        for (int kc = 0; kc < 2; ++kc) {
            qh[kc] = as_bf16x8(*(const u16x8*)(q_hi + qrow + kc * 32 + l4 * 8));
            ql[kc] = as_bf16x8(*(const u16x8*)(q_lo + qrow + kc * 32 + l4 * 8));
        }
    }

    f32x4 facc[4];
#pragma unroll
    for (int j = 0; j < 4; ++j) facc[j] = (f32x4){0.f, 0.f, 0.f, 0.f};
    float lsum = 0.f;

    const char* gbase_p = (const char*)kv + (((size_t)(b * NT)) << 15) +
                          w * 8192 + lane * 16;
    char* lw = (char*)kvbuf + w * 8192 + lane * 16;
    const char* lb = (const char*)kvbuf;

    f4 rr[8];

    // ---- prologue: reg-load tile t_begin, write LDS, barrier ----
    {
        const char* gt = gbase_p + (((size_t)t_begin) << 15);
#pragma unroll
        for (int s = 0; s < 8; ++s) rr[s] = *(const f4*)(gt + s * 1024);
#pragma unroll
        for (int s = 0; s < 8; ++s) *(f4*)(lw + s * 1024) = rr[s];
    }
    __syncthreads();

    for (int kt = t_begin; kt < t_end; ++kt) {
        const bool more = (kt + 1 < t_end);
        // ---- issue next tile's global loads (latency hides under compute) ----
        if (more) {
            const char* gt = gbase_p + (((size_t)(kt + 1)) << 15);
#pragma unroll
            for (int s = 0; s < 8; ++s) rr[s] = *(const f4*)(gt + s * 1024);
        }
        __builtin_amdgcn_sched_barrier(0);  // pin load issue above compute

        // ---- QK^T swapped (A=K, B=Q): D[t][q], col=lane&15=q ----
        f32x4 sc[4];
#pragma unroll
        for (int j = 0; j < 4; ++j) sc[j] = (f32x4){0.f, 0.f, 0.f, 0.f};
        __builtin_amdgcn_s_setprio(1);
#pragma unroll
        for (int kc = 0; kc < 2; ++kc) {
#pragma unroll
            for (int j2 = 0; j2 < 4; ++j2) {
                int f = kc * 4 + j2;
                bf16x8 h = as_bf16x8(*(const u16x8*)(lb + f * 1024 + lane * 16));
                bf16x8 l = as_bf16x8(*(const u16x8*)(lb + 8192 + f * 1024 + lane * 16));
                sc[j2] = MFMA16(h, qh[kc], sc[j2]);   // Kh*Qh
                sc[j2] = MFMA16(l, qh[kc], sc[j2]);   // Kl*Qh
                sc[j2] = MFMA16(h, ql[kc], sc[j2]);   // Kh*Ql
            }
        }
        __builtin_amdgcn_s_setprio(0);

        // ---- scale, mult-mask (diag only), exp, packed P-write, lsum ----
        const bool diag = (kt == i);
#pragma unroll
        for (int j2 = 0; j2 < 4; ++j2) {
            u16x4 p4;
#pragma unroll
            for (int reg = 0; reg < 4; ++reg) {
                float s = sc[j2][reg] * 0.125f;
                if (diag) {
                    int qr = w * 16 + l15;              // q row in tile
                    int tg = j2 * 16 + l4 * 4 + reg;    // t col in tile
                    if (tg > qr) s = 0.f;
                }
                float p = __expf(s);
                lsum += p;
                p4[reg] = f2bf(p);
            }
            int byte = (l15 * 128 + j2 * 32 + l4 * 8) ^ ((l15 & 7) << 4);
            *(u16x4*)((char*)plds[w] + byte) = p4;
        }

        // ---- PV: facc += P @ (Vhi + Vlo) ----
        __builtin_amdgcn_s_setprio(1);
#pragma unroll
        for (int c2 = 0; c2 < 2; ++c2) {
            int byteA = (l15 * 128 + c2 * 64 + l4 * 16) ^ ((l15 & 7) << 4);
            bf16x8 pf = as_bf16x8(*(const u16x8*)((const char*)plds[w] + byteA));
#pragma unroll
            for (int j = 0; j < 4; ++j) {
                int f = c2 * 4 + j;
                bf16x8 vh = as_bf16x8(*(const u16x8*)(lb + 16384 + f * 1024 + lane * 16));
                bf16x8 vl = as_bf16x8(*(const u16x8*)(lb + 24576 + f * 1024 + lane * 16));
                facc[j] = MFMA16(pf, vh, facc[j]);
                facc[j] = MFMA16(pf, vl, facc[j]);
            }
        }
        __builtin_amdgcn_s_setprio(0);

        // ---- tile boundary: all waves done reading kvbuf, then overwrite ----
        if (more) {
            __syncthreads();
#pragma unroll
            for (int s = 0; s < 8; ++s) *(f4*)(lw + s * 1024) = rr[s];
            __syncthreads();
        }
    }

    // ---- l-reduce: sum across l4 groups (lanes sharing l15) ----
    {
        float rs = lsum;
        rs += __shfl_xor(rs, 16);
        rs += __shfl_xor(rs, 32);
        const size_t slot = (size_t)b * NSL + bxr;
        if (l4 == 0)
            l_part[slot * 64 + w * 16 + l15] = rs;

        // ---- write facc partials ----
        float* fp = facc_part + slot * 4096;
#pragma unroll
        for (int j = 0; j < 4; ++j) {
#pragma unroll
            for (int reg = 0; reg < 4; ++reg) {
                int row = w * 16 + l4 * 4 + reg, a = j * 16 + l15;
                fp[row * 64 + a] = facc[j][reg];
            }
        }
    }
}

// ---------------------------------------------------------------------------
// Kernel 4: combine partials + closed-form masked region, write output (f4).
// ---------------------------------------------------------------------------
__launch_bounds__(256)
__global__ void combine_kernel(const float* __restrict__ facc_part,
                               const float* __restrict__ l_part,
                               const float* __restrict__ sufv,
                               float* __restrict__ out) {
    const int i = blockIdx.x;
    const int b = blockIdx.y;
    const int tid = threadIdx.x;
    const int g = i >> 3;
    const int nch = g + 1;
    const size_t slot0 = (size_t)b * NSL + 4 * g * (g + 1) + (i & 7) * nch;
    __shared__ float linv[64];
    __shared__ float sv[64];
    if (tid < 64) {
        float l = (float)(64 * (NT - 1 - i));
        for (int cc = 0; cc < nch; ++cc) l += l_part[(slot0 + cc) * 64 + tid];
        linv[tid] = 1.f / l;
        sv[tid] = sufv[((size_t)(b * 64 + tid)) * 64 + i];
    }
    __syncthreads();
    float* ob = out + ((size_t)(b * SS + i * 64)) * AA;
#pragma unroll
    for (int k = 0; k < 4; ++k) {
        int e = (tid + k * 256) * 4;
        int row = e >> 6, a = e & 63;
        f4 acc = {sv[a], sv[a + 1], sv[a + 2], sv[a + 3]};
        for (int cc = 0; cc < nch; ++cc) {
            f4 v = *(const f4*)(facc_part + (slot0 + cc) * 4096 + e);
            acc += v;
        }
        acc *= linv[row];
        *(f4*)(ob + e) = acc;
    }
}

// ---------------------------------------------------------------------------
extern "C" void kernel_launch(void* const* d_in, const int* in_sizes, int n_in,
                              void* d_out, int out_size, void* d_ws, size_t ws_size,
                              hipStream_t stream) {
    const float* query = (const float*)d_in[0];
    const float* key   = (const float*)d_in[1];
    const float* value = (const float*)d_in[2];
    const float* Wq    = (const float*)d_in[3];
    const float* bq    = (const float*)d_in[4];
    const float* Wk    = (const float*)d_in[5];
    const float* bk    = (const float*)d_in[6];
    const float* Wv    = (const float*)d_in[7];
    const float* bv    = (const float*)d_in[8];

    char* ws = (char*)d_ws;
    const size_t MB = 1u << 20;
    unsigned short* q_hi = (unsigned short*)(ws + 0 * MB);    // 2 MB
    unsigned short* q_lo = (unsigned short*)(ws + 2 * MB);    // 2 MB
    unsigned short* kv   = (unsigned short*)(ws + 4 * MB);    // 8 MB
    float* sufv      = (float*)(ws + 12 * MB);                // 64 KB
    float* l_part    = (float*)(ws + 13 * MB);                // 295 KB
    float* facc_part = (float*)(ws + 14 * MB);                // 18.9 MB
    unsigned short* wt_h = (unsigned short*)(ws + 34 * MB);   // 192 KB
    unsigned short* wt_l = wt_h + 3 * AA * EE;                // 192 KB

    split_w_kernel<<<(3 * EE * AA + 255) / 256, 256, 0, stream>>>(Wq, Wk, Wv, wt_h, wt_l);
    proj_kernel<<<dim3(BB * SS / 64, 3), 256, 0, stream>>>(
        query, key, value, bq, bk, bv, wt_h, wt_l, q_hi, q_lo, kv);
    sufv_kernel<<<BB * AA, 64, 0, stream>>>(kv, sufv);
    attn_chunk_kernel<<<dim3(NSL, BB), 256, 0, stream>>>(
        q_hi, q_lo, kv, facc_part, l_part);
    combine_kernel<<<dim3(NT, BB), 256, 0, stream>>>(facc_part, l_part, sufv, (float*)d_out);
}